// Round 2
// baseline (2039.562 us; speedup 1.0000x reference)
//
#include <hip/hip_runtime.h>
#include <hip/hip_cooperative_groups.h>

namespace cg = cooperative_groups;

// NeuralBPDecoder: sparse BP over a 0.1%-dense parity matrix, fully fused.
// One persistent cooperative kernel: zero counters + transpose-init, CSR
// build (one 512MB H scan — the HBM floor, ~81us), 15x (v->c, c->v) gather
// phases on transposed (V,B)/(C,B) state (coalesced 128B batch gathers,
// L2-resident), epilogue sigmoid. grid.sync() between phases replaces 30+
// kernel launches (~10us each) that dominated round 1.

#define C_NUM 8192
#define V_NUM 16384
#define B_NUM 32
#define RW 64   // max nnz per row (mean 16.4, Binomial tail << 64)
#define CW 32   // max nnz per col (mean 8.2, Binomial tail << 32)

#define GRID_BLOCKS 256
#define BLOCK_THREADS 1024
#define NTH (GRID_BLOCKS * BLOCK_THREADS)   // 262144 threads, all co-resident

__global__ __launch_bounds__(BLOCK_THREADS, 4)
void bp_fused(const float* __restrict__ H,
              const float* __restrict__ synd,
              const float* __restrict__ llr,
              const float* __restrict__ w_vc_p,
              const float* __restrict__ w_cv_p,
              const float* __restrict__ damp_p,
              int* __restrict__ row_cnt, int* __restrict__ col_cnt,
              int* __restrict__ row_idx, int* __restrict__ col_idx,
              float* __restrict__ beliefs_a, float* __restrict__ beliefs_b,
              float* __restrict__ cmsg,
              float* __restrict__ ssign_t, float* __restrict__ llr_t,
              float* __restrict__ out) {
    cg::grid_group grid = cg::this_grid();
    const int tid = blockIdx.x * blockDim.x + threadIdx.x;

    // ---- Phase 0: zero CSR counters + transpose-init state ----
    for (int i = tid; i < C_NUM + V_NUM; i += NTH) {
        if (i < C_NUM) row_cnt[i] = 0;
        else           col_cnt[i - C_NUM] = 0;
    }
    for (int t = tid; t < V_NUM * B_NUM; t += NTH) {
        int b = t & (B_NUM - 1);
        int v = t >> 5;
        float x = llr[b * V_NUM + v];
        beliefs_a[t] = x;
        llr_t[t] = x;
    }
    for (int t = tid; t < C_NUM * B_NUM; t += NTH) {
        int b = t & (B_NUM - 1);
        int c = t >> 5;
        ssign_t[t] = 1.0f - 2.0f * synd[b * C_NUM + c];
    }
    grid.sync();

    // ---- Phase 1: build CSR (row-wise + col-wise) from dense H ----
    {
        const int total4 = C_NUM * V_NUM / 4;   // 33.5M float4s = 512 MB
        for (int t = tid; t < total4; t += NTH) {
            float4 hv = ((const float4*)H)[t];
            int e = t * 4;
            float vals[4] = {hv.x, hv.y, hv.z, hv.w};
#pragma unroll
            for (int k = 0; k < 4; ++k) {
                if (vals[k] != 0.0f) {
                    int ee = e + k;
                    int c = ee >> 14;              // V = 2^14
                    int v = ee & (V_NUM - 1);
                    int rs = atomicAdd(&row_cnt[c], 1);
                    if (rs < RW) row_idx[c * RW + rs] = v;
                    int cs = atomicAdd(&col_cnt[v], 1);
                    if (cs < CW) col_idx[v * CW + cs] = c;
                }
            }
        }
    }
    grid.sync();

    // ---- Phase 2: 15 BP iterations ----
    const float w_vc = w_vc_p[0];
    const float w_cv = w_cv_p[0];
    const float d    = damp_p[0];

    float* cur = beliefs_a;
    float* nxt = beliefs_b;
    for (int it = 0; it < 15; ++it) {
        // v->c: one thread per (c,b); 32 lanes share c -> contiguous gather
        {
            int t = tid;          // C_NUM*B_NUM == NTH exactly
            int b = t & (B_NUM - 1);
            int c = t >> 5;
            int n = row_cnt[c];
            if (n > RW) n = RW;
            const int* __restrict__ idx = &row_idx[c * RW];
            float sum = 0.0f;
            for (int j = 0; j < n; ++j)
                sum += cur[idx[j] * B_NUM + b];
            cmsg[t] = ssign_t[t] * tanhf(0.5f * w_vc * sum);
        }
        grid.sync();
        // c->v: two items per thread (V_NUM*B_NUM == 2*NTH)
#pragma unroll
        for (int r = 0; r < 2; ++r) {
            int t = tid + r * NTH;
            int b = t & (B_NUM - 1);
            int v = t >> 5;
            int n = col_cnt[v];
            if (n > CW) n = CW;
            const int* __restrict__ idx = &col_idx[v * CW];
            float sum = 0.0f;
            for (int j = 0; j < n; ++j)
                sum += cmsg[idx[j] * B_NUM + b];
            nxt[t] = d * cur[t] + (1.0f - d) * (llr_t[t] + w_cv * sum);
        }
        grid.sync();
        float* tmp = cur; cur = nxt; nxt = tmp;
    }

    // ---- Phase 3: epilogue sigmoid(-beliefs), transpose back to (B,V) ----
#pragma unroll
    for (int r = 0; r < 2; ++r) {
        int t = tid + r * NTH;
        int v = t & (V_NUM - 1);
        int b = t >> 14;
        float x = cur[v * B_NUM + b];
        out[t] = 1.0f / (1.0f + __expf(x));
    }
}

extern "C" void kernel_launch(void* const* d_in, const int* in_sizes, int n_in,
                              void* d_out, int out_size, void* d_ws, size_t ws_size,
                              hipStream_t stream) {
    const float* synd = (const float*)d_in[0];   // (B, C)
    const float* H    = (const float*)d_in[1];   // (C, V)
    const float* llr  = (const float*)d_in[2];   // (B, V)
    const float* w_vc = (const float*)d_in[3];
    const float* w_cv = (const float*)d_in[4];
    const float* damp = (const float*)d_in[5];
    float* out = (float*)d_out;

    char* ws = (char*)d_ws;
    size_t off = 0;
    int* row_cnt = (int*)(ws + off); off += (size_t)C_NUM * 4;
    int* col_cnt = (int*)(ws + off); off += (size_t)V_NUM * 4;
    int* row_idx = (int*)(ws + off); off += (size_t)C_NUM * RW * 4;
    int* col_idx = (int*)(ws + off); off += (size_t)V_NUM * CW * 4;
    float* beliefs_a = (float*)(ws + off); off += (size_t)V_NUM * B_NUM * 4;
    float* beliefs_b = (float*)(ws + off); off += (size_t)V_NUM * B_NUM * 4;
    float* cmsg      = (float*)(ws + off); off += (size_t)C_NUM * B_NUM * 4;
    float* ssign_t   = (float*)(ws + off); off += (size_t)C_NUM * B_NUM * 4;
    float* llr_t     = (float*)(ws + off); off += (size_t)V_NUM * B_NUM * 4;

    void* args[] = {
        (void*)&H, (void*)&synd, (void*)&llr,
        (void*)&w_vc, (void*)&w_cv, (void*)&damp,
        (void*)&row_cnt, (void*)&col_cnt, (void*)&row_idx, (void*)&col_idx,
        (void*)&beliefs_a, (void*)&beliefs_b, (void*)&cmsg,
        (void*)&ssign_t, (void*)&llr_t, (void*)&out
    };
    hipLaunchCooperativeKernel((const void*)bp_fused,
                               dim3(GRID_BLOCKS), dim3(BLOCK_THREADS),
                               args, 0, stream);
}

// Round 3
// 1012.465 us; speedup vs baseline: 2.0145x; 2.0145x over previous
//
#include <hip/hip_runtime.h>

// NeuralBPDecoder: sparse BP over a 0.1%-dense parity matrix.
// Multi-launch structure (kernel boundary = global barrier; grid.sync() on
// MI355X costs ~45us/sync — measured round 2 — vs ~3-10us per graph-replayed
// launch). CSR rebuilt each call from dense H (512MB scan = HBM floor ~85us).
// Phases use transposed (V,B)/(C,B) state for coalesced 128B batch gathers,
// int4 index loads for 4x memory-level parallelism in the gather chain, and
// a fast exp-based tanh(x/2).

#define C_NUM 8192
#define V_NUM 16384
#define B_NUM 32
#define RW 64   // max nnz per row (mean 16.4; Binomial tail << 64)
#define CW 32   // max nnz per col (mean 8.2; Binomial tail << 32)

// Fused: CSR build (one 512MB H scan) + state transpose-init.
// Different threads touch disjoint arrays; no intra-kernel ordering needed.
__global__ void build_and_init(const float* __restrict__ H,
                               const float* __restrict__ llr,
                               const float* __restrict__ synd,
                               int* __restrict__ row_cnt, int* __restrict__ col_cnt,
                               int* __restrict__ row_idx, int* __restrict__ col_idx,
                               float* __restrict__ beliefs, float* __restrict__ llr_t,
                               float* __restrict__ ssign_t) {
    const int tid = blockIdx.x * blockDim.x + threadIdx.x;
    const int nth = gridDim.x * blockDim.x;

    // transpose-init beliefs/llr_t (B,V)->(V,B) and syndrome sign (B,C)->(C,B)
    for (int t = tid; t < V_NUM * B_NUM; t += nth) {
        int b = t & (B_NUM - 1);
        int v = t >> 5;
        float x = llr[b * V_NUM + v];
        beliefs[t] = x;
        llr_t[t] = x;
    }
    for (int t = tid; t < C_NUM * B_NUM; t += nth) {
        int b = t & (B_NUM - 1);
        int c = t >> 5;
        ssign_t[t] = 1.0f - 2.0f * synd[b * C_NUM + c];
    }

    // sparse scan of H
    const int total4 = C_NUM * V_NUM / 4;
    for (int t = tid; t < total4; t += nth) {
        float4 hv = ((const float4*)H)[t];
        int e = t * 4;
        float vals[4] = {hv.x, hv.y, hv.z, hv.w};
#pragma unroll
        for (int k = 0; k < 4; ++k) {
            if (vals[k] != 0.0f) {
                int ee = e + k;
                int c = ee >> 14;            // V = 2^14
                int v = ee & (V_NUM - 1);
                int rs = atomicAdd(&row_cnt[c], 1);
                if (rs < RW) row_idx[c * RW + rs] = v;
                int cs = atomicAdd(&col_cnt[v], 1);
                if (cs < CW) col_idx[v * CW + cs] = c;
            }
        }
    }
}

__device__ __forceinline__ float fast_tanh_half(float x) {
    // tanh(x/2) = sign(x) * (1 - e^-|x|) / (1 + e^-|x|)
    float ax = fabsf(x);
    float e = __expf(-ax);
    float th = (1.0f - e) / (1.0f + e);
    return copysignf(th, x);
}

// v->c: cmsg[c,b] = sign[c,b] * tanh(0.5 * w_vc * sum_{v in row c} beliefs[v,b])
__global__ void vc_kernel(const float* __restrict__ cur,
                          const int* __restrict__ row_cnt,
                          const int* __restrict__ row_idx,
                          const float* __restrict__ ssign_t,
                          const float* __restrict__ w_vc_p,
                          float* __restrict__ cmsg) {
    int t = blockIdx.x * blockDim.x + threadIdx.x;
    int b = t & (B_NUM - 1);
    int c = t >> 5;
    int n = row_cnt[c];
    if (n > RW) n = RW;
    const int4* __restrict__ idx4 = (const int4*)&row_idx[c * RW];
    float sum = 0.0f;
    int k4 = (n + 3) >> 2;
    for (int k = 0; k < k4; ++k) {
        int4 q = idx4[k];               // 16B broadcast across the 32 b-lanes
        int j = 4 * k;                  // 4 independent gathers in flight
        float s0 = (j     < n) ? cur[q.x * B_NUM + b] : 0.0f;
        float s1 = (j + 1 < n) ? cur[q.y * B_NUM + b] : 0.0f;
        float s2 = (j + 2 < n) ? cur[q.z * B_NUM + b] : 0.0f;
        float s3 = (j + 3 < n) ? cur[q.w * B_NUM + b] : 0.0f;
        sum += (s0 + s1) + (s2 + s3);
    }
    cmsg[t] = ssign_t[t] * fast_tanh_half(w_vc_p[0] * sum);
}

// c->v: out[v,b] = d*cur[v,b] + (1-d)*(llr[v,b] + w_cv * sum_{c in col v} cmsg[c,b])
__global__ void cv_kernel(const float* __restrict__ cmsg,
                          const int* __restrict__ col_cnt,
                          const int* __restrict__ col_idx,
                          const float* __restrict__ llr_t,
                          const float* __restrict__ cur,
                          float* __restrict__ nxt,
                          const float* __restrict__ w_cv_p,
                          const float* __restrict__ damp_p) {
    int t = blockIdx.x * blockDim.x + threadIdx.x;
    int b = t & (B_NUM - 1);
    int v = t >> 5;
    int n = col_cnt[v];
    if (n > CW) n = CW;
    const int4* __restrict__ idx4 = (const int4*)&col_idx[v * CW];
    float sum = 0.0f;
    int k4 = (n + 3) >> 2;
    for (int k = 0; k < k4; ++k) {
        int4 q = idx4[k];
        int j = 4 * k;
        float s0 = (j     < n) ? cmsg[q.x * B_NUM + b] : 0.0f;
        float s1 = (j + 1 < n) ? cmsg[q.y * B_NUM + b] : 0.0f;
        float s2 = (j + 2 < n) ? cmsg[q.z * B_NUM + b] : 0.0f;
        float s3 = (j + 3 < n) ? cmsg[q.w * B_NUM + b] : 0.0f;
        sum += (s0 + s1) + (s2 + s3);
    }
    float d = damp_p[0];
    nxt[t] = d * cur[t] + (1.0f - d) * (llr_t[t] + w_cv_p[0] * sum);
}

// out[b,v] = sigmoid(-beliefs[v,b])
__global__ void final_kernel(const float* __restrict__ beliefs,
                             float* __restrict__ out) {
    int t = blockIdx.x * blockDim.x + threadIdx.x;
    int v = t & (V_NUM - 1);
    int b = t >> 14;
    float x = beliefs[v * B_NUM + b];
    out[t] = 1.0f / (1.0f + __expf(x));
}

extern "C" void kernel_launch(void* const* d_in, const int* in_sizes, int n_in,
                              void* d_out, int out_size, void* d_ws, size_t ws_size,
                              hipStream_t stream) {
    const float* synd = (const float*)d_in[0];   // (B, C)
    const float* H    = (const float*)d_in[1];   // (C, V)
    const float* llr  = (const float*)d_in[2];   // (B, V)
    const float* w_vc = (const float*)d_in[3];
    const float* w_cv = (const float*)d_in[4];
    const float* damp = (const float*)d_in[5];
    float* out = (float*)d_out;

    char* ws = (char*)d_ws;
    size_t off = 0;
    int* row_cnt = (int*)(ws + off); off += (size_t)C_NUM * 4;
    int* col_cnt = (int*)(ws + off); off += (size_t)V_NUM * 4;
    int* row_idx = (int*)(ws + off); off += (size_t)C_NUM * RW * 4;
    int* col_idx = (int*)(ws + off); off += (size_t)V_NUM * CW * 4;
    float* beliefs_a = (float*)(ws + off); off += (size_t)V_NUM * B_NUM * 4;
    float* beliefs_b = (float*)(ws + off); off += (size_t)V_NUM * B_NUM * 4;
    float* cmsg      = (float*)(ws + off); off += (size_t)C_NUM * B_NUM * 4;
    float* ssign_t   = (float*)(ws + off); off += (size_t)C_NUM * B_NUM * 4;
    float* llr_t     = (float*)(ws + off); off += (size_t)V_NUM * B_NUM * 4;

    // zero CSR counters (ws arrives poisoned 0xAA)
    hipMemsetAsync(row_cnt, 0, (size_t)(C_NUM + V_NUM) * 4, stream);

    build_and_init<<<8192, 256, 0, stream>>>(H, llr, synd,
                                             row_cnt, col_cnt, row_idx, col_idx,
                                             beliefs_a, llr_t, ssign_t);

    float* cur = beliefs_a;
    float* nxt = beliefs_b;
    for (int it = 0; it < 15; ++it) {
        vc_kernel<<<(C_NUM * B_NUM) / 256, 256, 0, stream>>>(
            cur, row_cnt, row_idx, ssign_t, w_vc, cmsg);
        cv_kernel<<<(V_NUM * B_NUM) / 256, 256, 0, stream>>>(
            cmsg, col_cnt, col_idx, llr_t, cur, nxt, w_cv, damp);
        float* tmp = cur; cur = nxt; nxt = tmp;
    }
    final_kernel<<<(V_NUM * B_NUM) / 256, 256, 0, stream>>>(cur, out);
}